// Round 3
// baseline (78740.436 us; speedup 1.0000x reference)
//
#include <hip/hip_runtime.h>
#include <cstdint>
#include <cstddef>

// Problem constants
#define NN 32768
#define DD 16

__device__ __forceinline__ float sigf(float x) { return 1.0f / (1.0f + __expf(-x)); }
__device__ __forceinline__ float tanhfast(float x) { return 1.0f - 2.0f / (1.0f + __expf(2.0f * x)); }

__device__ __forceinline__ float4 fma4(float4 a, float4 b, float4 c) {
    c.x = fmaf(a.x, b.x, c.x);
    c.y = fmaf(a.y, b.y, c.y);
    c.z = fmaf(a.z, b.z, c.z);
    c.w = fmaf(a.w, b.w, c.w);
    return c;
}

// CK-style barrier: drains LDS counters ONLY (no vmcnt(0)) so global prefetch
// loads / streaming stores stay in flight across the per-step barriers.
__device__ __forceinline__ void sync_lds() {
    asm volatile("s_waitcnt lgkmcnt(0)\n\ts_barrier" ::: "memory");
}

// pair-repetition macros (named registers — arrays defeated SROA in R1/R2 and
// forced per-step weight re-fetch from memory: 33 GB FETCH_SIZE, VGPR=84)
#define REPP8(M) M(0,1) M(2,3) M(4,5) M(6,7) M(8,9) M(10,11) M(12,13) M(14,15)
#define REPP16(M) M(0,1) M(2,3) M(4,5) M(6,7) M(8,9) M(10,11) M(12,13) M(14,15) \
                  M(16,17) M(18,19) M(20,21) M(22,23) M(24,25) M(26,27) M(28,29) M(30,31)

// ---------------------------------------------------------------------------
// GEMM: out[m][n] = sum_k X[m][k] * W[n][k] + b1[n] + b2[n]
// ---------------------------------------------------------------------------
template <int K>
__global__ __launch_bounds__(256) void gemm_bias(const float* __restrict__ X,
                                                 const float* __restrict__ W,
                                                 const float* __restrict__ b1,
                                                 const float* __restrict__ b2,
                                                 float* __restrict__ out, int N) {
    __shared__ __align__(16) float As[64][68];
    __shared__ __align__(16) float Bs[64][68];
    int tid = threadIdx.x;
    int m0 = blockIdx.x * 64, n0 = blockIdx.y * 64;
    int tx = tid & 15, ty = tid >> 4;
    float acc[4][4] = {};
    for (int kc = 0; kc < K; kc += 64) {
#pragma unroll
        for (int e = 0; e < 4; e++) {
            int idx = e * 256 + tid;
            int row = idx >> 4;
            int kb = (idx & 15) * 4;
            *(float4*)&As[row][kb] = *(const float4*)(X + (size_t)(m0 + row) * K + kc + kb);
            *(float4*)&Bs[row][kb] = *(const float4*)(W + (size_t)(n0 + row) * K + kc + kb);
        }
        __syncthreads();
#pragma unroll 8
        for (int k = 0; k < 64; k++) {
            float a[4], b[4];
#pragma unroll
            for (int i = 0; i < 4; i++) a[i] = As[ty * 4 + i][k];
#pragma unroll
            for (int i = 0; i < 4; i++) b[i] = Bs[tx * 4 + i][k];
#pragma unroll
            for (int i = 0; i < 4; i++)
#pragma unroll
                for (int jj = 0; jj < 4; jj++) acc[i][jj] = fmaf(a[i], b[jj], acc[i][jj]);
        }
        __syncthreads();
    }
#pragma unroll
    for (int jj = 0; jj < 4; jj++) {
        int n = n0 + tx * 4 + jj;
        float bb = b1[n] + b2[n];
#pragma unroll
        for (int i = 0; i < 4; i++) {
            out[(size_t)(m0 + ty * 4 + i) * N + n] = acc[i][jj] + bb;
        }
    }
}

// ---------------------------------------------------------------------------
// Batched r-LSTM (T=16, H=128). Weights in NAMED float4 registers.
// ---------------------------------------------------------------------------
__global__ __launch_bounds__(1024) void rlstm_kernel(const float* __restrict__ XGX,
                                                     const int* __restrict__ nbr,
                                                     const float* __restrict__ Whh,
                                                     float* __restrict__ hagg) {
    __shared__ __align__(16) float h_s[16][128];
    __shared__ __align__(16) float g_s[16][512];
    __shared__ int node_s[16];
    int tid = threadIdx.x;
    int j = tid >> 1;       // gate col 0..511
    int half = tid & 1;     // K half
    const float4* wp = (const float4*)(Whh + (size_t)j * 128 + half * 64);
#define DECLRW(i, jj) float4 rw##i = wp[i], rw##jj = wp[jj];
    REPP8(DECLRW)
#undef DECLRW

    float c0 = 0.f, c1 = 0.f;
    for (int e = tid; e < 16 * 128; e += 1024) ((float*)h_s)[e] = 0.f;
    int r0 = blockIdx.x * 16;
    __syncthreads();

    for (int t = 0; t < DD; t++) {
        if (tid < 16) node_s[tid] = nbr[(size_t)(r0 + tid) * DD + t];
        for (int r = 0; r < 16; r++) {
            const float4* hp = (const float4*)(&h_s[r][half * 64]);
            float4 a0 = {0, 0, 0, 0}, a1 = {0, 0, 0, 0};
#define RDOT(i, jj) { float4 h0 = hp[i], h1 = hp[jj]; a0 = fma4(rw##i, h0, a0); a1 = fma4(rw##jj, h1, a1); }
            REPP8(RDOT)
#undef RDOT
            float s = (a0.x + a0.y) + (a0.z + a0.w) + ((a1.x + a1.y) + (a1.z + a1.w));
            s += __shfl_xor(s, 1, 64);
            if (half == 0) g_s[r][j] = s;
        }
        __syncthreads();
#pragma unroll
        for (int p = 0; p < 2; p++) {
            int idx = tid + p * 1024;
            int r = idx >> 7, hc = idx & 127;
            const float* xrow = XGX + (size_t)node_s[r] * 512;
            float gi = g_s[r][hc] + xrow[hc];
            float gf = g_s[r][128 + hc] + xrow[128 + hc];
            float gg = g_s[r][256 + hc] + xrow[256 + hc];
            float go = g_s[r][384 + hc] + xrow[384 + hc];
            float c = (p == 0) ? c0 : c1;
            c = sigf(gf) * c + sigf(gi) * tanhfast(gg);
            if (p == 0) c0 = c; else c1 = c;
            h_s[r][hc] = sigf(go) * tanhfast(c);
        }
        __syncthreads();
    }
#pragma unroll
    for (int p = 0; p < 2; p++) {
        int idx = tid + p * 1024;
        int r = idx >> 7, hc = idx & 127;
        hagg[(size_t)(r0 + r) * 128 + hc] = h_s[r][hc];
    }
}

// ---------------------------------------------------------------------------
// Sequential o-LSTM, H=128. 256 threads (4 waves, 1/SIMD, 512-VGPR budget).
// Thread tid owns gate cols tid (i/f) and 256+tid (g/o): 64 NAMED float4
// weights = 256 VGPRs. h broadcast via same-address ds_read_b128; xg
// prefetched one 4-step block ahead; HS stored scalar-coalesced, never
// drained (lgkmcnt-only barriers).
// ---------------------------------------------------------------------------
__global__ __launch_bounds__(256, 1) void olstm128_kernel(const float* __restrict__ XGO,
                                                          const float* __restrict__ Whh,
                                                          float* __restrict__ HS) {
    __shared__ __align__(16) float h_s[128];
    __shared__ __align__(16) float g_s[512];
    const int tid = threadIdx.x;
    const int jB = 256 + tid;
    // col A (i/f) is always sigmoid; col B: tid<128 -> g (tanh), else o (sigmoid)
    // unified activation: act = A + B / (1 + exp(K*s))
    const float Ab = (tid < 128) ? 1.f : 0.f;
    const float Bb = (tid < 128) ? -2.f : 1.f;
    const float Kb = (tid < 128) ? 2.f : -1.f;

    const float4* wpA = (const float4*)(Whh + (size_t)tid * 128);
    const float4* wpB = (const float4*)(Whh + (size_t)jB * 128);
#define DECLW(i, jj) float4 wa##i = wpA[i], wa##jj = wpA[jj], wb##i = wpB[i], wb##jj = wpB[jj];
    REPP16(DECLW)
#undef DECLW

    if (tid < 128) h_s[tid] = 0.f;
    float c = 0.f;

    float xa0 = XGO[(size_t)0 * 512 + tid], xa1 = XGO[(size_t)1 * 512 + tid];
    float xa2 = XGO[(size_t)2 * 512 + tid], xa3 = XGO[(size_t)3 * 512 + tid];
    float xb0 = XGO[(size_t)0 * 512 + jB], xb1 = XGO[(size_t)1 * 512 + jB];
    float xb2 = XGO[(size_t)2 * 512 + jB], xb3 = XGO[(size_t)3 * 512 + jB];
    sync_lds();

#define DOTP(i, jj) { float4 h0 = h4[i], h1 = h4[jj]; \
        aA0 = fma4(wa##i, h0, aA0); aB0 = fma4(wb##i, h0, aB0); \
        aA1 = fma4(wa##jj, h1, aA1); aB1 = fma4(wb##jj, h1, aB1); }

#define OSTEP(T, XA, XB) { \
        const float4* h4 = (const float4*)h_s; \
        float4 aA0 = {0,0,0,0}, aA1 = {0,0,0,0}, aB0 = {0,0,0,0}, aB1 = {0,0,0,0}; \
        REPP16(DOTP) \
        float sA = (((aA0.x+aA0.y)+(aA0.z+aA0.w)) + ((aA1.x+aA1.y)+(aA1.z+aA1.w))) + (XA); \
        float sB = (((aB0.x+aB0.y)+(aB0.z+aB0.w)) + ((aB1.x+aB1.y)+(aB1.z+aB1.w))) + (XB); \
        float gA = 1.0f / (1.0f + __expf(-sA)); \
        float gB = Ab + Bb / (1.0f + __expf(Kb * sB)); \
        g_s[tid] = gA; g_s[jB] = gB; \
        sync_lds(); \
        if (tid < 128) { \
            float gi = g_s[tid], gf = g_s[128 + tid], gg = g_s[256 + tid], go = g_s[384 + tid]; \
            c = gf * c + gi * gg; \
            float h = go * tanhfast(c); \
            h_s[tid] = h; \
            HS[(size_t)(T) * 128 + tid] = h; \
        } \
        sync_lds(); }

    for (int t = 0; t < NN; t += 4) {
        // prefetch next block's xg (rows t+4..t+7; tail reads 4 rows past XGO
        // into adjacent workspace — values never used)
        float na0 = XGO[(size_t)(t + 4) * 512 + tid], na1 = XGO[(size_t)(t + 5) * 512 + tid];
        float na2 = XGO[(size_t)(t + 6) * 512 + tid], na3 = XGO[(size_t)(t + 7) * 512 + tid];
        float nb0 = XGO[(size_t)(t + 4) * 512 + jB], nb1 = XGO[(size_t)(t + 5) * 512 + jB];
        float nb2 = XGO[(size_t)(t + 6) * 512 + jB], nb3 = XGO[(size_t)(t + 7) * 512 + jB];
        OSTEP(t + 0, xa0, xb0)
        OSTEP(t + 1, xa1, xb1)
        OSTEP(t + 2, xa2, xb2)
        OSTEP(t + 3, xa3, xb3)
        xa0 = na0; xa1 = na1; xa2 = na2; xa3 = na3;
        xb0 = nb0; xb1 = nb1; xb2 = nb2; xb3 = nb3;
    }
#undef OSTEP
#undef DOTP
}

// ---------------------------------------------------------------------------
// Sequential o-LSTM, H=64. 256 threads (4 waves), 1 gate col each:
// 16 NAMED float4 weights = 64 VGPRs.
// ---------------------------------------------------------------------------
__global__ __launch_bounds__(256, 1) void olstm64_kernel(const float* __restrict__ XGO,
                                                         const float* __restrict__ Whh,
                                                         float* __restrict__ HS) {
    __shared__ __align__(16) float h_s[64];
    __shared__ __align__(16) float g_s[256];
    const int tid = threadIdx.x;
    const int gate = tid >> 6;  // 0=i 1=f 2=g 3=o (wave-uniform)
    const float Aa = (gate == 2) ? 1.f : 0.f;
    const float Ba = (gate == 2) ? -2.f : 1.f;
    const float Ka = (gate == 2) ? 2.f : -1.f;

    const float4* wp = (const float4*)(Whh + (size_t)tid * 64);
#define DECLW64(i, jj) float4 w##i = wp[i], w##jj = wp[jj];
    REPP8(DECLW64)
#undef DECLW64

    if (tid < 64) h_s[tid] = 0.f;
    float c = 0.f;

    float xg0 = XGO[(size_t)0 * 256 + tid], xg1 = XGO[(size_t)1 * 256 + tid];
    float xg2 = XGO[(size_t)2 * 256 + tid], xg3 = XGO[(size_t)3 * 256 + tid];
    sync_lds();

#define DOT64(i, jj) { float4 h0 = h4[i], h1 = h4[jj]; \
        a0 = fma4(w##i, h0, a0); a1 = fma4(w##jj, h1, a1); }

#define OSTEP64(T, XG) { \
        const float4* h4 = (const float4*)h_s; \
        float4 a0 = {0,0,0,0}, a1 = {0,0,0,0}; \
        REPP8(DOT64) \
        float s = (((a0.x+a0.y)+(a0.z+a0.w)) + ((a1.x+a1.y)+(a1.z+a1.w))) + (XG); \
        float g = Aa + Ba / (1.0f + __expf(Ka * s)); \
        g_s[tid] = g; \
        sync_lds(); \
        if (tid < 64) { \
            float gi = g_s[tid], gf = g_s[64 + tid], gg = g_s[128 + tid], go = g_s[192 + tid]; \
            c = gf * c + gi * gg; \
            float h = go * tanhfast(c); \
            h_s[tid] = h; \
            HS[(size_t)(T) * 64 + tid] = h; \
        } \
        sync_lds(); }

    for (int t = 0; t < NN; t += 4) {
        float ng0 = XGO[(size_t)(t + 4) * 256 + tid], ng1 = XGO[(size_t)(t + 5) * 256 + tid];
        float ng2 = XGO[(size_t)(t + 6) * 256 + tid], ng3 = XGO[(size_t)(t + 7) * 256 + tid];
        OSTEP64(t + 0, xg0)
        OSTEP64(t + 1, xg1)
        OSTEP64(t + 2, xg2)
        OSTEP64(t + 3, xg3)
        xg0 = ng0; xg1 = ng1; xg2 = ng2; xg3 = ng3;
    }
#undef OSTEP64
#undef DOT64
}

// ---------------------------------------------------------------------------
// Fused relu + row L2-normalize (rows of 128), one wave per row.
// ---------------------------------------------------------------------------
__global__ __launch_bounds__(64) void relunorm_kernel(const float* __restrict__ in,
                                                      float* __restrict__ out) {
    int row = blockIdx.x;
    int lane = threadIdx.x;
    float2 v = ((const float2*)(in + (size_t)row * 128))[lane];
    v.x = fmaxf(v.x, 0.f);
    v.y = fmaxf(v.y, 0.f);
    float ss = v.x * v.x + v.y * v.y;
#pragma unroll
    for (int off = 32; off; off >>= 1) ss += __shfl_xor(ss, off, 64);
    float inv = 1.0f / fmaxf(sqrtf(ss), 1e-12f);
    float2 o;
    o.x = v.x * inv;
    o.y = v.y * inv;
    ((float2*)(out + (size_t)row * 128))[lane] = o;
}

// ---------------------------------------------------------------------------
extern "C" void kernel_launch(void* const* d_in, const int* in_sizes, int n_in,
                              void* d_out, int out_size, void* d_ws, size_t ws_size,
                              hipStream_t stream) {
    const float* x = (const float*)d_in[0];
    const int* nbr = (const int*)d_in[1];
    const float* Wih_r0 = (const float*)d_in[2];
    const float* Whh_r0 = (const float*)d_in[3];
    const float* bih_r0 = (const float*)d_in[4];
    const float* bhh_r0 = (const float*)d_in[5];
    const float* Wih_o0 = (const float*)d_in[6];
    const float* Whh_o0 = (const float*)d_in[7];
    const float* bih_o0 = (const float*)d_in[8];
    const float* bhh_o0 = (const float*)d_in[9];
    const float* Wlin0  = (const float*)d_in[10];
    const float* blin0  = (const float*)d_in[11];
    const float* bias0  = (const float*)d_in[12];
    const float* Wih_r1 = (const float*)d_in[13];
    const float* Whh_r1 = (const float*)d_in[14];
    const float* bih_r1 = (const float*)d_in[15];
    const float* bhh_r1 = (const float*)d_in[16];
    const float* Wih_o1 = (const float*)d_in[17];
    const float* Whh_o1 = (const float*)d_in[18];
    const float* bih_o1 = (const float*)d_in[19];
    const float* bhh_o1 = (const float*)d_in[20];
    const float* Wlin1  = (const float*)d_in[21];
    const float* blin1  = (const float*)d_in[22];
    const float* bias1  = (const float*)d_in[23];

    // workspace layout (bytes): A 64MB | C 16MB | D 16MB | E 16MB | F 16MB
    char* ws = (char*)d_ws;
    float* A = (float*)(ws);                              // XGX then XGO
    float* C = (float*)(ws + (size_t)64 * 1024 * 1024);   // h_agg
    float* Dt = (float*)(ws + (size_t)80 * 1024 * 1024);  // HS
    float* E = (float*)(ws + (size_t)96 * 1024 * 1024);   // X1
    float* F = (float*)(ws + (size_t)112 * 1024 * 1024);  // lin0 raw

    float* outp = (float*)d_out;

    // ----- layer 0 -----
    gemm_bias<128><<<dim3(NN / 64, 8), 256, 0, stream>>>(x, Wih_r0, bih_r0, bhh_r0, A, 512);
    rlstm_kernel<<<NN / 16, 1024, 0, stream>>>(A, nbr, Whh_r0, C);
    gemm_bias<128><<<dim3(NN / 64, 8), 256, 0, stream>>>(C, Wih_o0, bih_o0, bhh_o0, A, 512);
    olstm128_kernel<<<1, 256, 0, stream>>>(A, Whh_o0, Dt);
    gemm_bias<128><<<dim3(NN / 64, 2), 256, 0, stream>>>(Dt, Wlin0, blin0, bias0, F, 128);
    relunorm_kernel<<<NN, 64, 0, stream>>>(F, E);

    // ----- layer 1 -----
    gemm_bias<128><<<dim3(NN / 64, 8), 256, 0, stream>>>(E, Wih_r1, bih_r1, bhh_r1, A, 512);
    rlstm_kernel<<<NN / 16, 1024, 0, stream>>>(A, nbr, Whh_r1, C);
    gemm_bias<128><<<dim3(NN / 64, 4), 256, 0, stream>>>(C, Wih_o1, bih_o1, bhh_o1, A, 256);
    olstm64_kernel<<<1, 256, 0, stream>>>(A, Whh_o1, Dt);
    gemm_bias<64><<<dim3(NN / 64, 1), 256, 0, stream>>>(Dt, Wlin1, blin1, bias1, outp, 64);
}

// Round 5
// 72232.574 us; speedup vs baseline: 1.0901x; 1.0901x over previous
//
#include <hip/hip_runtime.h>
#include <cstdint>
#include <cstddef>

// Problem constants
#define NN 32768
#define DD 16

__device__ __forceinline__ float sigf(float x) { return 1.0f / (1.0f + __expf(-x)); }
__device__ __forceinline__ float tanhfast(float x) { return 1.0f - 2.0f / (1.0f + __expf(2.0f * x)); }

__device__ __forceinline__ float4 fma4(float4 a, float4 b, float4 c) {
    c.x = fmaf(a.x, b.x, c.x);
    c.y = fmaf(a.y, b.y, c.y);
    c.z = fmaf(a.z, b.z, c.z);
    c.w = fmaf(a.w, b.w, c.w);
    return c;
}

__device__ __forceinline__ float hsum8(float4 a, float4 b) {
    float4 s;
    s.x = a.x + b.x; s.y = a.y + b.y; s.z = a.z + b.z; s.w = a.w + b.w;
    return (s.x + s.y) + (s.z + s.w);
}

// Opaque no-op on each scalar component: asm results cannot be rematerialized,
// so the register allocator must keep the loaded weights live in VGPRs.
// (float4-level "+v" fails: "tied indirect register inputs" — R4.)
__device__ __forceinline__ void opaque4(float4& v) {
    asm volatile("" : "+v"(v.x), "+v"(v.y), "+v"(v.z), "+v"(v.w));
}

// CK-style barrier: drains LDS counters ONLY (no vmcnt(0)) so global prefetch
// loads / streaming stores stay in flight across the per-step barriers.
__device__ __forceinline__ void sync_lds() {
    asm volatile("s_waitcnt lgkmcnt(0)\n\ts_barrier" ::: "memory");
}

// repetition macros
#define REPP8(M) M(0,1) M(2,3) M(4,5) M(6,7) M(8,9) M(10,11) M(12,13) M(14,15)
#define REP16(M) M(0) M(1) M(2) M(3) M(4) M(5) M(6) M(7) M(8) M(9) M(10) M(11) M(12) M(13) M(14) M(15)
#define REP16P(M) M(0,0) M(1,1) M(2,0) M(3,1) M(4,0) M(5,1) M(6,0) M(7,1) \
                  M(8,0) M(9,1) M(10,0) M(11,1) M(12,0) M(13,1) M(14,0) M(15,1)
#define REP8L(M) M(0) M(1) M(2) M(3) M(4) M(5) M(6) M(7)
#define REP8P(M) M(0,0) M(1,1) M(2,0) M(3,1) M(4,0) M(5,1) M(6,0) M(7,1)

// ---------------------------------------------------------------------------
// GEMM: out[m][n] = sum_k X[m][k] * W[n][k] + b1[n] + b2[n]
// ---------------------------------------------------------------------------
template <int K>
__global__ __launch_bounds__(256) void gemm_bias(const float* __restrict__ X,
                                                 const float* __restrict__ W,
                                                 const float* __restrict__ b1,
                                                 const float* __restrict__ b2,
                                                 float* __restrict__ out, int N) {
    __shared__ __align__(16) float As[64][68];
    __shared__ __align__(16) float Bs[64][68];
    int tid = threadIdx.x;
    int m0 = blockIdx.x * 64, n0 = blockIdx.y * 64;
    int tx = tid & 15, ty = tid >> 4;
    float acc[4][4] = {};
    for (int kc = 0; kc < K; kc += 64) {
#pragma unroll
        for (int e = 0; e < 4; e++) {
            int idx = e * 256 + tid;
            int row = idx >> 4;
            int kb = (idx & 15) * 4;
            *(float4*)&As[row][kb] = *(const float4*)(X + (size_t)(m0 + row) * K + kc + kb);
            *(float4*)&Bs[row][kb] = *(const float4*)(W + (size_t)(n0 + row) * K + kc + kb);
        }
        __syncthreads();
#pragma unroll 8
        for (int k = 0; k < 64; k++) {
            float a[4], b[4];
#pragma unroll
            for (int i = 0; i < 4; i++) a[i] = As[ty * 4 + i][k];
#pragma unroll
            for (int i = 0; i < 4; i++) b[i] = Bs[tx * 4 + i][k];
#pragma unroll
            for (int i = 0; i < 4; i++)
#pragma unroll
                for (int jj = 0; jj < 4; jj++) acc[i][jj] = fmaf(a[i], b[jj], acc[i][jj]);
        }
        __syncthreads();
    }
#pragma unroll
    for (int jj = 0; jj < 4; jj++) {
        int n = n0 + tx * 4 + jj;
        float bb = b1[n] + b2[n];
#pragma unroll
        for (int i = 0; i < 4; i++) {
            out[(size_t)(m0 + ty * 4 + i) * N + n] = acc[i][jj] + bb;
        }
    }
}

// ---------------------------------------------------------------------------
// Batched r-LSTM (T=16, H=128) — unchanged (not the current bottleneck).
// ---------------------------------------------------------------------------
__global__ __launch_bounds__(1024) void rlstm_kernel(const float* __restrict__ XGX,
                                                     const int* __restrict__ nbr,
                                                     const float* __restrict__ Whh,
                                                     float* __restrict__ hagg) {
    __shared__ __align__(16) float h_s[16][128];
    __shared__ __align__(16) float g_s[16][512];
    __shared__ int node_s[16];
    int tid = threadIdx.x;
    int j = tid >> 1;       // gate col 0..511
    int half = tid & 1;     // K half
    const float4* wp = (const float4*)(Whh + (size_t)j * 128 + half * 64);
#define DECLRW(i, jj) float4 rw##i = wp[i], rw##jj = wp[jj];
    REPP8(DECLRW)
#undef DECLRW

    float c0 = 0.f, c1 = 0.f;
    for (int e = tid; e < 16 * 128; e += 1024) ((float*)h_s)[e] = 0.f;
    int r0 = blockIdx.x * 16;
    __syncthreads();

    for (int t = 0; t < DD; t++) {
        if (tid < 16) node_s[tid] = nbr[(size_t)(r0 + tid) * DD + t];
        for (int r = 0; r < 16; r++) {
            const float4* hp = (const float4*)(&h_s[r][half * 64]);
            float4 a0 = {0, 0, 0, 0}, a1 = {0, 0, 0, 0};
#define RDOT(i, jj) { float4 h0 = hp[i], h1 = hp[jj]; a0 = fma4(rw##i, h0, a0); a1 = fma4(rw##jj, h1, a1); }
            REPP8(RDOT)
#undef RDOT
            float s = (a0.x + a0.y) + (a0.z + a0.w) + ((a1.x + a1.y) + (a1.z + a1.w));
            s += __shfl_xor(s, 1, 64);
            if (half == 0) g_s[r][j] = s;
        }
        __syncthreads();
#pragma unroll
        for (int p = 0; p < 2; p++) {
            int idx = tid + p * 1024;
            int r = idx >> 7, hc = idx & 127;
            const float* xrow = XGX + (size_t)node_s[r] * 512;
            float gi = g_s[r][hc] + xrow[hc];
            float gf = g_s[r][128 + hc] + xrow[128 + hc];
            float gg = g_s[r][256 + hc] + xrow[256 + hc];
            float go = g_s[r][384 + hc] + xrow[384 + hc];
            float c = (p == 0) ? c0 : c1;
            c = sigf(gf) * c + sigf(gi) * tanhfast(gg);
            if (p == 0) c0 = c; else c1 = c;
            h_s[r][hc] = sigf(go) * tanhfast(c);
        }
        __syncthreads();
    }
#pragma unroll
    for (int p = 0; p < 2; p++) {
        int idx = tid + p * 1024;
        int r = idx >> 7, hc = idx & 127;
        hagg[(size_t)(r0 + r) * 128 + hc] = h_s[r][hc];
    }
}

// ---------------------------------------------------------------------------
// Sequential o-LSTM, H=128. 256 threads (4 waves, 1/SIMD, 512-VGPR budget).
// thread = (hidden unit n = tid>>1, K-half kh = tid&1), owns ALL 4 gate cols
// of unit n: 64 float4 weights = 256 VGPRs, remat-proof via per-component
// opaque asm. One barrier/step; h double-buffered in LDS; cell state
// replicated in both kh threads. HS stores stream, never barrier-drained.
// ---------------------------------------------------------------------------
__global__ __launch_bounds__(256, 1) void olstm128_kernel(const float* __restrict__ XGO,
                                                          const float* __restrict__ Whh,
                                                          float* __restrict__ HS) {
    __shared__ __align__(16) float h_s[2][128];
    const int tid = threadIdx.x;
    const int kh = tid & 1;
    const int n = tid >> 1;   // 0..127

    const float4* wip = (const float4*)(Whh + (size_t)(0 * 128 + n) * 128 + kh * 64);
    const float4* wfp = (const float4*)(Whh + (size_t)(1 * 128 + n) * 128 + kh * 64);
    const float4* wgp = (const float4*)(Whh + (size_t)(2 * 128 + n) * 128 + kh * 64);
    const float4* wop = (const float4*)(Whh + (size_t)(3 * 128 + n) * 128 + kh * 64);
#define DW(m) float4 wi##m = wip[m], wf##m = wfp[m], wg##m = wgp[m], wo##m = wop[m];
    REP16(DW)
#undef DW
#define OPQ(m) opaque4(wi##m); opaque4(wf##m); opaque4(wg##m); opaque4(wo##m);
    REP16(OPQ)
#undef OPQ

    if (kh == 0) h_s[0][n] = 0.f;
    float c = 0.f;

#define PLD(s, T) float pi##s = XGO[(size_t)(T) * 512 + n];        \
                  float pf##s = XGO[(size_t)(T) * 512 + 128 + n];  \
                  float pg##s = XGO[(size_t)(T) * 512 + 256 + n];  \
                  float po##s = XGO[(size_t)(T) * 512 + 384 + n];
    PLD(0, 0) PLD(1, 1) PLD(2, 2) PLD(3, 3)
#undef PLD
    __syncthreads();

#define ACCM(m, p) { float4 hm = h4[m];            \
        Ai##p = fma4(wi##m, hm, Ai##p);            \
        Af##p = fma4(wf##m, hm, Af##p);            \
        Ag##p = fma4(wg##m, hm, Ag##p);            \
        Ao##p = fma4(wo##m, hm, Ao##p); }

#define OSTEP(T, B, s) {                                                        \
        const float4* h4 = (const float4*)(&h_s[B][0]) + kh * 16;               \
        float4 Ai0 = {0,0,0,0}, Ai1 = {0,0,0,0}, Af0 = {0,0,0,0}, Af1 = {0,0,0,0}; \
        float4 Ag0 = {0,0,0,0}, Ag1 = {0,0,0,0}, Ao0 = {0,0,0,0}, Ao1 = {0,0,0,0}; \
        REP16P(ACCM)                                                            \
        float si = hsum8(Ai0, Ai1), sf = hsum8(Af0, Af1);                       \
        float sg = hsum8(Ag0, Ag1), so = hsum8(Ao0, Ao1);                       \
        si += __shfl_xor(si, 1, 64); sf += __shfl_xor(sf, 1, 64);               \
        sg += __shfl_xor(sg, 1, 64); so += __shfl_xor(so, 1, 64);               \
        si += pi##s; sf += pf##s; sg += pg##s; so += po##s;                     \
        float gi = sigf(si), gf = sigf(sf), gG = tanhfast(sg), go = sigf(so);   \
        c = gf * c + gi * gG;                                                   \
        float hh = go * tanhfast(c);                                            \
        if (kh == 0) { h_s[(B) ^ 1][n] = hh; HS[(size_t)(T) * 128 + n] = hh; }  \
        sync_lds(); }

    for (int t = 0; t < NN; t += 4) {
        // prefetch next block's xg (tail reads <=4 rows past XGO into adjacent
        // workspace; values never used)
#define NLD(s, T) float ni##s = XGO[(size_t)(T) * 512 + n];        \
                  float nf##s = XGO[(size_t)(T) * 512 + 128 + n];  \
                  float ng##s = XGO[(size_t)(T) * 512 + 256 + n];  \
                  float no##s = XGO[(size_t)(T) * 512 + 384 + n];
        NLD(0, t + 4) NLD(1, t + 5) NLD(2, t + 6) NLD(3, t + 7)
#undef NLD
        OSTEP(t + 0, 0, 0)
        OSTEP(t + 1, 1, 1)
        OSTEP(t + 2, 0, 2)
        OSTEP(t + 3, 1, 3)
        pi0 = ni0; pf0 = nf0; pg0 = ng0; po0 = no0;
        pi1 = ni1; pf1 = nf1; pg1 = ng1; po1 = no1;
        pi2 = ni2; pf2 = nf2; pg2 = ng2; po2 = no2;
        pi3 = ni3; pf3 = nf3; pg3 = ng3; po3 = no3;
    }
#undef OSTEP
#undef ACCM
}

// ---------------------------------------------------------------------------
// Sequential o-LSTM, H=64. 256 threads: thread = (n = tid>>2, gate-pair
// gg = (tid>>1)&1, K-half kh = tid&1). 16 float4 weights (2 gate cols x 32 K),
// opaque-pinned. shfl_xor(1) merges K-halves, shfl_xor(2) exchanges gate
// pairs; cell update replicated x4. One barrier/step.
// ---------------------------------------------------------------------------
__global__ __launch_bounds__(256, 1) void olstm64_kernel(const float* __restrict__ XGO,
                                                         const float* __restrict__ Whh,
                                                         float* __restrict__ HS) {
    __shared__ __align__(16) float h_s[2][64];
    const int tid = threadIdx.x;
    const int kh = tid & 1;
    const int gg = (tid >> 1) & 1;   // 0: gates (i,f)  1: gates (g,o)
    const int n = tid >> 2;          // 0..63

    const float4* wap = (const float4*)(Whh + (size_t)(gg * 128 + n) * 64 + kh * 32);
    const float4* wbp = (const float4*)(Whh + (size_t)(gg * 128 + 64 + n) * 64 + kh * 32);
#define DW64(m) float4 wa##m = wap[m], wb##m = wbp[m];
    REP8L(DW64)
#undef DW64
#define OPQ64(m) opaque4(wa##m); opaque4(wb##m);
    REP8L(OPQ64)
#undef OPQ64

    if ((tid & 3) == 0) h_s[0][n] = 0.f;
    float c = 0.f;

#define PLD64(s, T) float pa##s = XGO[(size_t)(T) * 256 + gg * 128 + n];       \
                    float pb##s = XGO[(size_t)(T) * 256 + gg * 128 + 64 + n];
    PLD64(0, 0) PLD64(1, 1) PLD64(2, 2) PLD64(3, 3)
#undef PLD64
    __syncthreads();

#define ACC64(m, p) { float4 hm = h4[m];          \
        Aa##p = fma4(wa##m, hm, Aa##p);           \
        Ab##p = fma4(wb##m, hm, Ab##p); }

#define OSTEP64(T, B, s) {                                                      \
        const float4* h4 = (const float4*)(&h_s[B][0]) + kh * 8;                \
        float4 Aa0 = {0,0,0,0}, Aa1 = {0,0,0,0}, Ab0 = {0,0,0,0}, Ab1 = {0,0,0,0}; \
        REP8P(ACC64)                                                            \
        float sa = hsum8(Aa0, Aa1), sb = hsum8(Ab0, Ab1);                       \
        sa += __shfl_xor(sa, 1, 64); sb += __shfl_xor(sb, 1, 64);               \
        sa += pa##s; sb += pb##s;                                               \
        float qa = __shfl_xor(sa, 2, 64), qb = __shfl_xor(sb, 2, 64);           \
        float si = gg ? qa : sa, sf = gg ? qb : sb;                             \
        float sg = gg ? sa : qa, so = gg ? sb : qb;                             \
        float gi = sigf(si), gf = sigf(sf), gG = tanhfast(sg), go = sigf(so);   \
        c = gf * c + gi * gG;                                                   \
        float hh = go * tanhfast(c);                                            \
        if ((tid & 3) == 0) { h_s[(B) ^ 1][n] = hh; HS[(size_t)(T) * 64 + n] = hh; } \
        sync_lds(); }

    for (int t = 0; t < NN; t += 4) {
#define NLD64(s, T) float na##s = XGO[(size_t)(T) * 256 + gg * 128 + n];       \
                    float nb##s = XGO[(size_t)(T) * 256 + gg * 128 + 64 + n];
        NLD64(0, t + 4) NLD64(1, t + 5) NLD64(2, t + 6) NLD64(3, t + 7)
#undef NLD64
        OSTEP64(t + 0, 0, 0)
        OSTEP64(t + 1, 1, 1)
        OSTEP64(t + 2, 0, 2)
        OSTEP64(t + 3, 1, 3)
        pa0 = na0; pb0 = nb0; pa1 = na1; pb1 = nb1;
        pa2 = na2; pb2 = nb2; pa3 = na3; pb3 = nb3;
    }
#undef OSTEP64
#undef ACC64
}

// ---------------------------------------------------------------------------
// Fused relu + row L2-normalize (rows of 128), one wave per row.
// ---------------------------------------------------------------------------
__global__ __launch_bounds__(64) void relunorm_kernel(const float* __restrict__ in,
                                                      float* __restrict__ out) {
    int row = blockIdx.x;
    int lane = threadIdx.x;
    float2 v = ((const float2*)(in + (size_t)row * 128))[lane];
    v.x = fmaxf(v.x, 0.f);
    v.y = fmaxf(v.y, 0.f);
    float ss = v.x * v.x + v.y * v.y;
#pragma unroll
    for (int off = 32; off; off >>= 1) ss += __shfl_xor(ss, off, 64);
    float inv = 1.0f / fmaxf(sqrtf(ss), 1e-12f);
    float2 o;
    o.x = v.x * inv;
    o.y = v.y * inv;
    ((float2*)(out + (size_t)row * 128))[lane] = o;
}

// ---------------------------------------------------------------------------
extern "C" void kernel_launch(void* const* d_in, const int* in_sizes, int n_in,
                              void* d_out, int out_size, void* d_ws, size_t ws_size,
                              hipStream_t stream) {
    const float* x = (const float*)d_in[0];
    const int* nbr = (const int*)d_in[1];
    const float* Wih_r0 = (const float*)d_in[2];
    const float* Whh_r0 = (const float*)d_in[3];
    const float* bih_r0 = (const float*)d_in[4];
    const float* bhh_r0 = (const float*)d_in[5];
    const float* Wih_o0 = (const float*)d_in[6];
    const float* Whh_o0 = (const float*)d_in[7];
    const float* bih_o0 = (const float*)d_in[8];
    const float* bhh_o0 = (const float*)d_in[9];
    const float* Wlin0  = (const float*)d_in[10];
    const float* blin0  = (const float*)d_in[11];
    const float* bias0  = (const float*)d_in[12];
    const float* Wih_r1 = (const float*)d_in[13];
    const float* Whh_r1 = (const float*)d_in[14];
    const float* bih_r1 = (const float*)d_in[15];
    const float* bhh_r1 = (const float*)d_in[16];
    const float* Wih_o1 = (const float*)d_in[17];
    const float* Whh_o1 = (const float*)d_in[18];
    const float* bih_o1 = (const float*)d_in[19];
    const float* bhh_o1 = (const float*)d_in[20];
    const float* Wlin1  = (const float*)d_in[21];
    const float* blin1  = (const float*)d_in[22];
    const float* bias1  = (const float*)d_in[23];

    // workspace layout (bytes): A 64MB | C 16MB | D 16MB | E 16MB | F 16MB
    char* ws = (char*)d_ws;
    float* A = (float*)(ws);                              // XGX then XGO
    float* C = (float*)(ws + (size_t)64 * 1024 * 1024);   // h_agg
    float* Dt = (float*)(ws + (size_t)80 * 1024 * 1024);  // HS
    float* E = (float*)(ws + (size_t)96 * 1024 * 1024);   // X1
    float* F = (float*)(ws + (size_t)112 * 1024 * 1024);  // lin0 raw

    float* outp = (float*)d_out;

    // ----- layer 0 -----
    gemm_bias<128><<<dim3(NN / 64, 8), 256, 0, stream>>>(x, Wih_r0, bih_r0, bhh_r0, A, 512);
    rlstm_kernel<<<NN / 16, 1024, 0, stream>>>(A, nbr, Whh_r0, C);
    gemm_bias<128><<<dim3(NN / 64, 8), 256, 0, stream>>>(C, Wih_o0, bih_o0, bhh_o0, A, 512);
    olstm128_kernel<<<1, 256, 0, stream>>>(A, Whh_o0, Dt);
    gemm_bias<128><<<dim3(NN / 64, 2), 256, 0, stream>>>(Dt, Wlin0, blin0, bias0, F, 128);
    relunorm_kernel<<<NN, 64, 0, stream>>>(F, E);

    // ----- layer 1 -----
    gemm_bias<128><<<dim3(NN / 64, 8), 256, 0, stream>>>(E, Wih_r1, bih_r1, bhh_r1, A, 512);
    rlstm_kernel<<<NN / 16, 1024, 0, stream>>>(A, nbr, Whh_r1, C);
    gemm_bias<128><<<dim3(NN / 64, 4), 256, 0, stream>>>(C, Wih_o1, bih_o1, bhh_o1, A, 256);
    olstm64_kernel<<<1, 256, 0, stream>>>(A, Whh_o1, Dt);
    gemm_bias<64><<<dim3(NN / 64, 1), 256, 0, stream>>>(Dt, Wlin1, blin1, bias1, outp, 64);
}

// Round 6
// 53458.301 us; speedup vs baseline: 1.4729x; 1.3512x over previous
//
#include <hip/hip_runtime.h>
#include <cstdint>
#include <cstddef>

// Problem constants
#define NN 32768
#define DD 16

__device__ __forceinline__ float sigf(float x) { return 1.0f / (1.0f + __expf(-x)); }
__device__ __forceinline__ float tanhfast(float x) { return 1.0f - 2.0f / (1.0f + __expf(2.0f * x)); }

__device__ __forceinline__ float4 fma4(float4 a, float4 b, float4 c) {
    c.x = fmaf(a.x, b.x, c.x);
    c.y = fmaf(a.y, b.y, c.y);
    c.z = fmaf(a.z, b.z, c.z);
    c.w = fmaf(a.w, b.w, c.w);
    return c;
}

__device__ __forceinline__ float hsum8(float4 a, float4 b) {
    float4 s;
    s.x = a.x + b.x; s.y = a.y + b.y; s.z = a.z + b.z; s.w = a.w + b.w;
    return (s.x + s.y) + (s.z + s.w);
}

// Opaque per-component pin: asm results can't be rematerialized.
__device__ __forceinline__ void opaque4(float4& v) {
    asm volatile("" : "+v"(v.x), "+v"(v.y), "+v"(v.z), "+v"(v.w));
}

// CK-style barrier: drains LDS counters ONLY (no vmcnt(0)) so global prefetch
// loads / streaming stores stay in flight across the per-step barriers.
__device__ __forceinline__ void sync_lds() {
    asm volatile("s_waitcnt lgkmcnt(0)\n\ts_barrier" ::: "memory");
}

// repetition macros
#define REPP8(M) M(0,1) M(2,3) M(4,5) M(6,7) M(8,9) M(10,11) M(12,13) M(14,15)
#define REP16(M) M(0) M(1) M(2) M(3) M(4) M(5) M(6) M(7) M(8) M(9) M(10) M(11) M(12) M(13) M(14) M(15)
#define REP16P(M) M(0,0) M(1,1) M(2,0) M(3,1) M(4,0) M(5,1) M(6,0) M(7,1) \
                  M(8,0) M(9,1) M(10,0) M(11,1) M(12,0) M(13,1) M(14,0) M(15,1)
#define REP8L(M) M(0) M(1) M(2) M(3) M(4) M(5) M(6) M(7)
#define REP8P(M) M(0,0) M(1,1) M(2,0) M(3,1) M(4,0) M(5,1) M(6,0) M(7,1)

// ---------------------------------------------------------------------------
// GEMM: out[m][n] = sum_k X[m][k] * W[n][k] + b1[n] + b2[n]
// ---------------------------------------------------------------------------
template <int K>
__global__ __launch_bounds__(256) void gemm_bias(const float* __restrict__ X,
                                                 const float* __restrict__ W,
                                                 const float* __restrict__ b1,
                                                 const float* __restrict__ b2,
                                                 float* __restrict__ out, int N) {
    __shared__ __align__(16) float As[64][68];
    __shared__ __align__(16) float Bs[64][68];
    int tid = threadIdx.x;
    int m0 = blockIdx.x * 64, n0 = blockIdx.y * 64;
    int tx = tid & 15, ty = tid >> 4;
    float acc[4][4] = {};
    for (int kc = 0; kc < K; kc += 64) {
#pragma unroll
        for (int e = 0; e < 4; e++) {
            int idx = e * 256 + tid;
            int row = idx >> 4;
            int kb = (idx & 15) * 4;
            *(float4*)&As[row][kb] = *(const float4*)(X + (size_t)(m0 + row) * K + kc + kb);
            *(float4*)&Bs[row][kb] = *(const float4*)(W + (size_t)(n0 + row) * K + kc + kb);
        }
        __syncthreads();
#pragma unroll 8
        for (int k = 0; k < 64; k++) {
            float a[4], b[4];
#pragma unroll
            for (int i = 0; i < 4; i++) a[i] = As[ty * 4 + i][k];
#pragma unroll
            for (int i = 0; i < 4; i++) b[i] = Bs[tx * 4 + i][k];
#pragma unroll
            for (int i = 0; i < 4; i++)
#pragma unroll
                for (int jj = 0; jj < 4; jj++) acc[i][jj] = fmaf(a[i], b[jj], acc[i][jj]);
        }
        __syncthreads();
    }
#pragma unroll
    for (int jj = 0; jj < 4; jj++) {
        int n = n0 + tx * 4 + jj;
        float bb = b1[n] + b2[n];
#pragma unroll
        for (int i = 0; i < 4; i++) {
            out[(size_t)(m0 + ty * 4 + i) * N + n] = acc[i][jj] + bb;
        }
    }
}

// ---------------------------------------------------------------------------
// Batched r-LSTM (T=16, H=128) — unchanged (not the current bottleneck).
// ---------------------------------------------------------------------------
__global__ __launch_bounds__(1024) void rlstm_kernel(const float* __restrict__ XGX,
                                                     const int* __restrict__ nbr,
                                                     const float* __restrict__ Whh,
                                                     float* __restrict__ hagg) {
    __shared__ __align__(16) float h_s[16][128];
    __shared__ __align__(16) float g_s[16][512];
    __shared__ int node_s[16];
    int tid = threadIdx.x;
    int j = tid >> 1;       // gate col 0..511
    int half = tid & 1;     // K half
    const float4* wp = (const float4*)(Whh + (size_t)j * 128 + half * 64);
#define DECLRW(i, jj) float4 rw##i = wp[i], rw##jj = wp[jj];
    REPP8(DECLRW)
#undef DECLRW

    float c0 = 0.f, c1 = 0.f;
    for (int e = tid; e < 16 * 128; e += 1024) ((float*)h_s)[e] = 0.f;
    int r0 = blockIdx.x * 16;
    __syncthreads();

    for (int t = 0; t < DD; t++) {
        if (tid < 16) node_s[tid] = nbr[(size_t)(r0 + tid) * DD + t];
        for (int r = 0; r < 16; r++) {
            const float4* hp = (const float4*)(&h_s[r][half * 64]);
            float4 a0 = {0, 0, 0, 0}, a1 = {0, 0, 0, 0};
#define RDOT(i, jj) { float4 h0 = hp[i], h1 = hp[jj]; a0 = fma4(rw##i, h0, a0); a1 = fma4(rw##jj, h1, a1); }
            REPP8(RDOT)
#undef RDOT
            float s = (a0.x + a0.y) + (a0.z + a0.w) + ((a1.x + a1.y) + (a1.z + a1.w));
            s += __shfl_xor(s, 1, 64);
            if (half == 0) g_s[r][j] = s;
        }
        __syncthreads();
#pragma unroll
        for (int p = 0; p < 2; p++) {
            int idx = tid + p * 1024;
            int r = idx >> 7, hc = idx & 127;
            const float* xrow = XGX + (size_t)node_s[r] * 512;
            float gi = g_s[r][hc] + xrow[hc];
            float gf = g_s[r][128 + hc] + xrow[128 + hc];
            float gg = g_s[r][256 + hc] + xrow[256 + hc];
            float go = g_s[r][384 + hc] + xrow[384 + hc];
            float c = (p == 0) ? c0 : c1;
            c = sigf(gf) * c + sigf(gi) * tanhfast(gg);
            if (p == 0) c0 = c; else c1 = c;
            h_s[r][hc] = sigf(go) * tanhfast(c);
        }
        __syncthreads();
    }
#pragma unroll
    for (int p = 0; p < 2; p++) {
        int idx = tid + p * 1024;
        int r = idx >> 7, hc = idx & 127;
        hagg[(size_t)(r0 + r) * 128 + hc] = h_s[r][hc];
    }
}

// ---------------------------------------------------------------------------
// Sequential o-LSTM, H=128. 512 threads (8 waves, 2/SIMD, 256-VGPR budget —
// inside the allocator's comfort zone, NO spill).
// thread = (unit n = tid>>2, gate-pair gp = (tid>>1)&1, K-half kh = tid&1):
// owns 2 gate cols x 64 K = 32 float4 = 128 weight VGPRs (opaque-pinned).
// h in LDS, double-buffered, DUAL-COPY with +16-bank stagger so the two
// kh address groups hit disjoint banks (R5: 8.4M conflicts from bank-aliased
// kh offsets). shfl_xor(1) merges K-halves, shfl_xor(2) exchanges gate pairs.
// One lgkmcnt-only barrier/step; xg prefetched 4 steps ahead; HS stores
// stream (never barrier-drained).
// ---------------------------------------------------------------------------
__global__ __launch_bounds__(512, 2) void olstm128_kernel(const float* __restrict__ XGO,
                                                          const float* __restrict__ Whh,
                                                          float* __restrict__ HS) {
    // copy A: h[0..128) at [0..128); copy B: h[j] at [144+j] (only j>=64 used,
    // i.e. floats 208..272). 208 % 32 = 16 -> kh=1 reads start 16 banks after
    // kh=0 reads -> disjoint bank groups every ds_read_b128.
    __shared__ __align__(16) float h_s[2][272];
    const int tid = threadIdx.x;
    const int kh = tid & 1;
    const int gp = (tid >> 1) & 1;   // 0: gates (i,f)  1: gates (g,o)
    const int n = tid >> 2;          // 0..127

    const float4* wap = (const float4*)(Whh + (size_t)(gp * 256 + n) * 128 + kh * 64);
    const float4* wbp = (const float4*)(Whh + (size_t)(gp * 256 + 128 + n) * 128 + kh * 64);
#define DW(m) float4 wa##m = wap[m], wb##m = wbp[m];
    REP16(DW)
#undef DW
#define OPQ(m) opaque4(wa##m); opaque4(wb##m);
    REP16(OPQ)
#undef OPQ

    for (int e = tid; e < 2 * 272; e += 512) ((float*)h_s)[e] = 0.f;
    float c = 0.f;

#define PLD(s, T) float pa##s = XGO[(size_t)(T) * 512 + gp * 256 + n];        \
                  float pb##s = XGO[(size_t)(T) * 512 + gp * 256 + 128 + n];
    PLD(0, 0) PLD(1, 1) PLD(2, 2) PLD(3, 3)
#undef PLD
    __syncthreads();

#define ACCM(m, p) { float4 hm = h4[m];            \
        Aa##p = fma4(wa##m, hm, Aa##p);            \
        Ab##p = fma4(wb##m, hm, Ab##p); }

#define OSTEP(T, B, s) {                                                          \
        const float4* h4 = (const float4*)(&h_s[B][0] + (kh ? 208 : 0));          \
        float4 Aa0 = {0,0,0,0}, Aa1 = {0,0,0,0}, Ab0 = {0,0,0,0}, Ab1 = {0,0,0,0}; \
        REP16P(ACCM)                                                              \
        float sa = hsum8(Aa0, Aa1), sb = hsum8(Ab0, Ab1);                         \
        sa += __shfl_xor(sa, 1, 64); sb += __shfl_xor(sb, 1, 64);                 \
        sa += pa##s; sb += pb##s;                                                 \
        float ga = gp ? tanhfast(sa) : sigf(sa);                                  \
        float gb = sigf(sb);                                                      \
        float qa = __shfl_xor(ga, 2, 64), qb = __shfl_xor(gb, 2, 64);             \
        float gi = gp ? qa : ga, gf = gp ? qb : gb;                               \
        float gg = gp ? ga : qa, go = gp ? gb : qb;                               \
        c = gf * c + gi * gg;                                                     \
        float hh = go * tanhfast(c);                                              \
        if ((tid & 3) == 0) {                                                     \
            h_s[(B) ^ 1][n] = hh;                                                 \
            if (n >= 64) h_s[(B) ^ 1][144 + n] = hh;                              \
            HS[(size_t)(T) * 128 + n] = hh;                                       \
        }                                                                         \
        sync_lds(); }

    for (int t = 0; t < NN; t += 4) {
        // prefetch next block's xg (tail reads <=4 rows past XGO into adjacent
        // workspace; values never used)
#define NLD(s, T) float na##s = XGO[(size_t)(T) * 512 + gp * 256 + n];        \
                  float nb##s = XGO[(size_t)(T) * 512 + gp * 256 + 128 + n];
        NLD(0, t + 4) NLD(1, t + 5) NLD(2, t + 6) NLD(3, t + 7)
#undef NLD
        OSTEP(t + 0, 0, 0)
        OSTEP(t + 1, 1, 1)
        OSTEP(t + 2, 0, 2)
        OSTEP(t + 3, 1, 3)
        pa0 = na0; pb0 = nb0; pa1 = na1; pb1 = nb1;
        pa2 = na2; pb2 = nb2; pa3 = na3; pb3 = nb3;
    }
#undef OSTEP
#undef ACCM
}

// ---------------------------------------------------------------------------
// Sequential o-LSTM, H=64. 256 threads: thread = (n = tid>>2, gate-pair
// gg = (tid>>1)&1, K-half kh = tid&1). 16 float4 weights, opaque-pinned
// (64 VGPRs + overhead ~110 — no spill risk). Same staggered dual-copy of h:
// copy B at base 80 (80%32=16), kh=1 reads floats [112..144) = h[32..64).
// ---------------------------------------------------------------------------
__global__ __launch_bounds__(256, 1) void olstm64_kernel(const float* __restrict__ XGO,
                                                         const float* __restrict__ Whh,
                                                         float* __restrict__ HS) {
    __shared__ __align__(16) float h_s[2][144];
    const int tid = threadIdx.x;
    const int kh = tid & 1;
    const int gg = (tid >> 1) & 1;   // 0: gates (i,f)  1: gates (g,o)
    const int n = tid >> 2;          // 0..63

    const float4* wap = (const float4*)(Whh + (size_t)(gg * 128 + n) * 64 + kh * 32);
    const float4* wbp = (const float4*)(Whh + (size_t)(gg * 128 + 64 + n) * 64 + kh * 32);
#define DW64(m) float4 wa##m = wap[m], wb##m = wbp[m];
    REP8L(DW64)
#undef DW64
#define OPQ64(m) opaque4(wa##m); opaque4(wb##m);
    REP8L(OPQ64)
#undef OPQ64

    for (int e = tid; e < 2 * 144; e += 256) ((float*)h_s)[e] = 0.f;
    float c = 0.f;

#define PLD64(s, T) float pa##s = XGO[(size_t)(T) * 256 + gg * 128 + n];       \
                    float pb##s = XGO[(size_t)(T) * 256 + gg * 128 + 64 + n];
    PLD64(0, 0) PLD64(1, 1) PLD64(2, 2) PLD64(3, 3)
#undef PLD64
    __syncthreads();

#define ACC64(m, p) { float4 hm = h4[m];          \
        Aa##p = fma4(wa##m, hm, Aa##p);           \
        Ab##p = fma4(wb##m, hm, Ab##p); }

#define OSTEP64(T, B, s) {                                                      \
        const float4* h4 = (const float4*)(&h_s[B][0] + (kh ? 112 : 0));        \
        float4 Aa0 = {0,0,0,0}, Aa1 = {0,0,0,0}, Ab0 = {0,0,0,0}, Ab1 = {0,0,0,0}; \
        REP8P(ACC64)                                                            \
        float sa = hsum8(Aa0, Aa1), sb = hsum8(Ab0, Ab1);                       \
        sa += __shfl_xor(sa, 1, 64); sb += __shfl_xor(sb, 1, 64);               \
        sa += pa##s; sb += pb##s;                                               \
        float ga = gg ? tanhfast(sa) : sigf(sa);                                \
        float gb = sigf(sb);                                                    \
        float qa = __shfl_xor(ga, 2, 64), qb = __shfl_xor(gb, 2, 64);           \
        float gi = gg ? qa : ga, gf = gg ? qb : gb;                             \
        float gG = gg ? ga : qa, go = gg ? gb : qb;                             \
        c = gf * c + gi * gG;                                                   \
        float hh = go * tanhfast(c);                                            \
        if ((tid & 3) == 0) {                                                   \
            h_s[(B) ^ 1][n] = hh;                                               \
            if (n >= 32) h_s[(B) ^ 1][80 + n] = hh;                             \
            HS[(size_t)(T) * 64 + n] = hh;                                      \
        }                                                                       \
        sync_lds(); }

    for (int t = 0; t < NN; t += 4) {
#define NLD64(s, T) float na##s = XGO[(size_t)(T) * 256 + gg * 128 + n];       \
                    float nb##s = XGO[(size_t)(T) * 256 + gg * 128 + 64 + n];
        NLD64(0, t + 4) NLD64(1, t + 5) NLD64(2, t + 6) NLD64(3, t + 7)
#undef NLD64
        OSTEP64(t + 0, 0, 0)
        OSTEP64(t + 1, 1, 1)
        OSTEP64(t + 2, 0, 2)
        OSTEP64(t + 3, 1, 3)
        pa0 = na0; pb0 = nb0; pa1 = na1; pb1 = nb1;
        pa2 = na2; pb2 = nb2; pa3 = na3; pb3 = nb3;
    }
#undef OSTEP64
#undef ACC64
}

// ---------------------------------------------------------------------------
// Fused relu + row L2-normalize (rows of 128), one wave per row.
// ---------------------------------------------------------------------------
__global__ __launch_bounds__(64) void relunorm_kernel(const float* __restrict__ in,
                                                      float* __restrict__ out) {
    int row = blockIdx.x;
    int lane = threadIdx.x;
    float2 v = ((const float2*)(in + (size_t)row * 128))[lane];
    v.x = fmaxf(v.x, 0.f);
    v.y = fmaxf(v.y, 0.f);
    float ss = v.x * v.x + v.y * v.y;
#pragma unroll
    for (int off = 32; off; off >>= 1) ss += __shfl_xor(ss, off, 64);
    float inv = 1.0f / fmaxf(sqrtf(ss), 1e-12f);
    float2 o;
    o.x = v.x * inv;
    o.y = v.y * inv;
    ((float2*)(out + (size_t)row * 128))[lane] = o;
}

// ---------------------------------------------------------------------------
extern "C" void kernel_launch(void* const* d_in, const int* in_sizes, int n_in,
                              void* d_out, int out_size, void* d_ws, size_t ws_size,
                              hipStream_t stream) {
    const float* x = (const float*)d_in[0];
    const int* nbr = (const int*)d_in[1];
    const float* Wih_r0 = (const float*)d_in[2];
    const float* Whh_r0 = (const float*)d_in[3];
    const float* bih_r0 = (const float*)d_in[4];
    const float* bhh_r0 = (const float*)d_in[5];
    const float* Wih_o0 = (const float*)d_in[6];
    const float* Whh_o0 = (const float*)d_in[7];
    const float* bih_o0 = (const float*)d_in[8];
    const float* bhh_o0 = (const float*)d_in[9];
    const float* Wlin0  = (const float*)d_in[10];
    const float* blin0  = (const float*)d_in[11];
    const float* bias0  = (const float*)d_in[12];
    const float* Wih_r1 = (const float*)d_in[13];
    const float* Whh_r1 = (const float*)d_in[14];
    const float* bih_r1 = (const float*)d_in[15];
    const float* bhh_r1 = (const float*)d_in[16];
    const float* Wih_o1 = (const float*)d_in[17];
    const float* Whh_o1 = (const float*)d_in[18];
    const float* bih_o1 = (const float*)d_in[19];
    const float* bhh_o1 = (const float*)d_in[20];
    const float* Wlin1  = (const float*)d_in[21];
    const float* blin1  = (const float*)d_in[22];
    const float* bias1  = (const float*)d_in[23];

    // workspace layout (bytes): A 64MB | C 16MB | D 16MB | E 16MB | F 16MB
    char* ws = (char*)d_ws;
    float* A = (float*)(ws);                              // XGX then XGO
    float* C = (float*)(ws + (size_t)64 * 1024 * 1024);   // h_agg
    float* Dt = (float*)(ws + (size_t)80 * 1024 * 1024);  // HS
    float* E = (float*)(ws + (size_t)96 * 1024 * 1024);   // X1
    float* F = (float*)(ws + (size_t)112 * 1024 * 1024);  // lin0 raw

    float* outp = (float*)d_out;

    // ----- layer 0 -----
    gemm_bias<128><<<dim3(NN / 64, 8), 256, 0, stream>>>(x, Wih_r0, bih_r0, bhh_r0, A, 512);
    rlstm_kernel<<<NN / 16, 1024, 0, stream>>>(A, nbr, Whh_r0, C);
    gemm_bias<128><<<dim3(NN / 64, 8), 256, 0, stream>>>(C, Wih_o0, bih_o0, bhh_o0, A, 512);
    olstm128_kernel<<<1, 512, 0, stream>>>(A, Whh_o0, Dt);
    gemm_bias<128><<<dim3(NN / 64, 2), 256, 0, stream>>>(Dt, Wlin0, blin0, bias0, F, 128);
    relunorm_kernel<<<NN, 64, 0, stream>>>(F, E);

    // ----- layer 1 -----
    gemm_bias<128><<<dim3(NN / 64, 8), 256, 0, stream>>>(E, Wih_r1, bih_r1, bhh_r1, A, 512);
    rlstm_kernel<<<NN / 16, 1024, 0, stream>>>(A, nbr, Whh_r1, C);
    gemm_bias<128><<<dim3(NN / 64, 4), 256, 0, stream>>>(C, Wih_o1, bih_o1, bhh_o1, A, 256);
    olstm64_kernel<<<1, 256, 0, stream>>>(A, Whh_o1, Dt);
    gemm_bias<64><<<dim3(NN / 64, 1), 256, 0, stream>>>(Dt, Wlin1, blin1, bias1, outp, 64);
}